// Round 7
// baseline (140.953 us; speedup 1.0000x reference)
//
#include <hip/hip_runtime.h>
#include <cmath>

#define N_NODES 50000
#define N_EDGES 800000
#define N_FEAT 128
#define DIM 64
#define N_GRAPHS 512
#define GGRID ((N_NODES + 63) / 64)         // 782 gemm1 tiles / buckets
#define NBKT GGRID                          // bucket = dst>>6
#define BH_BLK 256                          // scatter blocks (edge pass)
#define EPB (N_EDGES / BH_BLK)              // 3125 edges per scatter block
#define BKT_CAP 2048                        // fixed slot region per bucket

typedef short short8 __attribute__((ext_vector_type(8)));
typedef float floatx4 __attribute__((ext_vector_type(4)));

// bf16 storage helpers (RNE). Storage-only: all math in fp32.
__device__ __forceinline__ unsigned short f2bf(float f) {
  union { float f; unsigned int u; } v; v.f = f;
  return (unsigned short)((v.u + 0x7FFFu + ((v.u >> 16) & 1u)) >> 16);
}
__device__ __forceinline__ float bf2f(unsigned short u) {
  union { unsigned int u; float f; } v; v.u = (unsigned int)u << 16;
  return v.f;
}

// ---------------------------------------------------------------------------
// dispatch 0 (replaces the gcur memset): block 0 zeros gcur; blocks 1..32
// split W1 into bf16 head+residual, transposed [c][k] so gemm W-frag reads
// are linear short8 (16KB total -> L1-resident during the gemm).
__global__ __launch_bounds__(256) void init_split(const float* __restrict__ W1,
                                                  unsigned short* __restrict__ w1sh,
                                                  unsigned short* __restrict__ w1sl,
                                                  int* __restrict__ gcur) {
  const int tid = threadIdx.x;
  if (blockIdx.x == 0) {
    for (int i = tid; i < NBKT; i += 256) gcur[i] = 0;
  } else {
    int idx = (blockIdx.x - 1) * 256 + tid;   // idx = c*128 + kk
    int kk = idx & 127, c = idx >> 7;
    float f = W1[kk * 64 + c];
    unsigned short h = f2bf(f);
    unsigned short l = f2bf(f - bf2f(h));
    w1sh[idx] = h;
    w1sl[idx] = l;
  }
}

// ---------------------------------------------------------------------------
// Split-bf16 MFMA gemm1, x-in-LDS / W-from-L1: h1[64x64] = x[64x128]@W1.
// R0's verified staging+swizzle+fragment code (absmax-identical), but LDS
// holds ONLY the x tile (32KB hi+lo, swizzled) -> 5 blocks/CU, so the
// scatter arm stays co-resident (R0's 64KB version broke the R11 pairing;
// R1's zero-LDS version had stride-512B uncoalesced A-loads: 4x over-fetch).
// acc = xh@Wh + xh@Wl + xl@Wh (xl@Wl ~2^-17 dropped) -> fp32-equivalent.
// C/D layout (m89-verified): col = lane&15, row = 4*(lane>>4) + reg.
__device__ __forceinline__ void gemm1_mfma(const float* __restrict__ x,
                                           const unsigned short* __restrict__ w1sh,
                                           const unsigned short* __restrict__ w1sl,
                                           unsigned short* __restrict__ h1,
                                           int row0, int tid,
                                           unsigned short* sXh,
                                           unsigned short* sXl) {
  // stage x tile: 64 rows x 128 cols fp32, split -> bf16 hi/lo, XOR-swizzled
  // (coalesced: consecutive tid -> consecutive float4 within a row)
#pragma unroll
  for (int i = 0; i < 8; i++) {
    int fid = i * 256 + tid;              // 0..2047 float4s
    int r = fid >> 5;                     // 32 float4 per row
    int c4 = (fid & 31) << 2;
    int gr = row0 + r;
    float4 v = make_float4(0.f, 0.f, 0.f, 0.f);
    if (gr < N_NODES) v = *(const float4*)&x[(size_t)gr * N_FEAT + c4];
    ushort4 h, l;
    h.x = f2bf(v.x); l.x = f2bf(v.x - bf2f(h.x));
    h.y = f2bf(v.y); l.y = f2bf(v.y - bf2f(h.y));
    h.z = f2bf(v.z); l.z = f2bf(v.z - bf2f(h.z));
    h.w = f2bf(v.w); l.w = f2bf(v.w - bf2f(h.w));
    int idx = r * 128 + (c4 ^ ((r & 15) << 3));
    *(ushort4*)&sXh[idx] = h;
    *(ushort4*)&sXl[idx] = l;
  }
  __syncthreads();

  const int lane = tid & 63, w = tid >> 6;
  const int g = lane >> 4, c15 = lane & 15;
  const int ra = (w << 4) + c15;          // A row in tile; ra&15 == c15
  const int akey = c15 << 3;              // XOR swizzle key (elem units)
  floatx4 acc[4];
#pragma unroll
  for (int i = 0; i < 4; i++) acc[i] = (floatx4){0.f, 0.f, 0.f, 0.f};

#pragma unroll
  for (int kb = 0; kb < 128; kb += 32) {
    const int ka = kb + g * 8;            // consistent k-slice for A and B
    short8 ah = *(const short8*)&sXh[ra * 128 + (ka ^ akey)];
    short8 al = *(const short8*)&sXl[ra * 128 + (ka ^ akey)];
#pragma unroll
    for (int ct = 0; ct < 4; ct++) {
      const int cb = ct * 16 + c15;       // B column; same ka slice (L1-hot)
      short8 bh = *(const short8*)&w1sh[cb * 128 + ka];
      short8 bl = *(const short8*)&w1sl[cb * 128 + ka];
      acc[ct] = __builtin_amdgcn_mfma_f32_16x16x32_bf16(ah, bh, acc[ct], 0, 0, 0);
      acc[ct] = __builtin_amdgcn_mfma_f32_16x16x32_bf16(ah, bl, acc[ct], 0, 0, 0);
      acc[ct] = __builtin_amdgcn_mfma_f32_16x16x32_bf16(al, bh, acc[ct], 0, 0, 0);
    }
  }

  // epilogue: col = ct*16 + c15, row = w*16 + g*4 + r
#pragma unroll
  for (int ct = 0; ct < 4; ct++) {
#pragma unroll
    for (int r = 0; r < 4; r++) {
      int gr = row0 + (w << 4) + (g << 2) + r;
      if (gr < N_NODES) h1[(size_t)gr * 64 + ct * 16 + c15] = f2bf(acc[ct][r]);
    }
  }
}

// ---------------------------------------------------------------------------
// dispatch 1 (fused front-end):
//   blocks [0,BH_BLK):  slotted bucket scatter — LDS histogram of dst>>6,
//                       chunk reservation via atomicAdd on gcur[782], then
//                       LDS-cursor scatter of packed (src<<6)|dst_local.
//   block  BH_BLK:      w2fc = W2@Wfc precompute.
//   blocks (BH_BLK..]:  gemm1 (x@W1 -> h1 bf16, split-bf16 MFMA).
// 32KB LDS -> 5 blocks/CU -> all 1039 blocks co-resident (R11 pairing).
__global__ __launch_bounds__(256) void fused_main(
    const float* __restrict__ x,
    const unsigned short* __restrict__ w1sh,
    const unsigned short* __restrict__ w1sl,
    unsigned short* __restrict__ h1, const int* __restrict__ src,
    const int* __restrict__ dst, int* __restrict__ gcur,
    unsigned int* __restrict__ ebuf, const float* __restrict__ W2,
    const float* __restrict__ Wfc, float* __restrict__ w2fc) {
  __shared__ __align__(16) unsigned short sXh[64 * 128];
  __shared__ __align__(16) unsigned short sXl[64 * 128];
  const int tid = threadIdx.x;
  if (blockIdx.x < BH_BLK) {
    int* lh = (int*)sXh;                    // [NBKT] block-local counts
    int* lbase = lh + NBKT;                 // [NBKT] reserved global slots
    int* lcur = (int*)sXl;                  // [NBKT] block-local cursors
    for (int i = tid; i < NBKT; i += 256) { lh[i] = 0; lcur[i] = 0; }
    __syncthreads();
    const int base = blockIdx.x * EPB;
    for (int j = tid; j < EPB; j += 256)
      atomicAdd(&lh[dst[base + j] >> 6], 1);
    __syncthreads();
    for (int i = tid; i < NBKT; i += 256) {
      int n = lh[i];
      lbase[i] = (n > 0) ? i * BKT_CAP + atomicAdd(&gcur[i], n) : 0;
    }
    __syncthreads();
    for (int j = tid; j < EPB; j += 256) {
      int e = base + j;
      int d = dst[e];
      int b = d >> 6;
      int pos = atomicAdd(&lcur[b], 1);
      unsigned int gpos = (unsigned int)(lbase[b] + pos);
      if (gpos < (unsigned int)((b + 1) * BKT_CAP))   // overflow guard
        ebuf[gpos] = ((unsigned int)src[e] << 6) | (unsigned int)(d & 63);
    }
  } else if (blockIdx.x == BH_BLK) {
    int k = tid;
    if (k < 64) {
      float s = 0.f;
#pragma unroll 8
      for (int j = 0; j < 64; j++) s += W2[k * 64 + j] * Wfc[j];
      w2fc[k] = s;
    }
  } else {
    gemm1_mfma(x, w1sh, w1sl, h1, (blockIdx.x - BH_BLK - 1) * 64, tid,
               sXh, sXl);
  }
}

// ---------------------------------------------------------------------------
// dispatch 2: per-bucket LDS CSR sort + layer-1 gather + relu + dot(w2fc)
// -> z[node]. 782 blocks x 1024 threads (16 waves x 4 nodes). Bucket region
// is the fixed slot range [b*BKT_CAP, b*BKT_CAP + gcur[b]); edges staged
// into LDS during the count pass -> ebuf read ONCE.
__global__ __launch_bounds__(1024, 8) void gather_z_fused(
    const unsigned short* __restrict__ h1,
    const unsigned int* __restrict__ ebuf,
    const int* __restrict__ gcur,
    const float* __restrict__ w2fc,
    float* __restrict__ z) {
  __shared__ unsigned int eL[BKT_CAP];
  __shared__ int colL[BKT_CAP];
  __shared__ int lstart[64];
  __shared__ int lcur[64];
  __shared__ float sw[64];
  const int tid = threadIdx.x;
  const int b = blockIdx.x;
  const int p0 = b * BKT_CAP;
  int cnt = gcur[b];
  if (cnt > BKT_CAP) cnt = BKT_CAP;                 // never triggers

  if (tid < 64) { lstart[tid] = 0; sw[tid] = w2fc[tid]; }
  __syncthreads();
  for (int i = tid; i < cnt; i += 1024) {           // stage + count
    unsigned int u = ebuf[p0 + i];
    eL[i] = u;
    atomicAdd(&lstart[u & 63], 1);
  }
  __syncthreads();
  if (tid < 64) {
    int v = lstart[tid], s = v;
#pragma unroll
    for (int off = 1; off < 64; off <<= 1) {
      int t = __shfl_up(s, off, 64);
      if (tid >= off) s += t;
    }
    lstart[tid] = s - v;
    lcur[tid] = s - v;
  }
  __syncthreads();
  for (int i = tid; i < cnt; i += 1024) {           // scatter from LDS
    unsigned int u = eL[i];
    int pos = atomicAdd(&lcur[u & 63], 1);
    colL[pos] = (int)(u >> 6);
  }
  __syncthreads();

  const int lane = tid & 63, w = tid >> 6;
  const int eo = lane >> 4, qfo = (lane & 15) << 2;
#pragma unroll
  for (int ni = 0; ni < 4; ni++) {
    const int r = ni * 16 + w;
    const int i1 = lcur[r];
    int i = lstart[r];
    float4 acc = make_float4(0.f, 0.f, 0.f, 0.f);
    for (; i + 16 <= i1; i += 16) {
      int s0 = colL[i + eo];
      int s1 = colL[i + 4 + eo];
      int s2 = colL[i + 8 + eo];
      int s3 = colL[i + 12 + eo];
      ushort4 u0 = *(const ushort4*)&h1[(size_t)s0 * 64 + qfo];
      ushort4 u1 = *(const ushort4*)&h1[(size_t)s1 * 64 + qfo];
      ushort4 u2 = *(const ushort4*)&h1[(size_t)s2 * 64 + qfo];
      ushort4 u3 = *(const ushort4*)&h1[(size_t)s3 * 64 + qfo];
      acc.x += (bf2f(u0.x) + bf2f(u1.x)) + (bf2f(u2.x) + bf2f(u3.x));
      acc.y += (bf2f(u0.y) + bf2f(u1.y)) + (bf2f(u2.y) + bf2f(u3.y));
      acc.z += (bf2f(u0.z) + bf2f(u1.z)) + (bf2f(u2.z) + bf2f(u3.z));
      acc.w += (bf2f(u0.w) + bf2f(u1.w)) + (bf2f(u2.w) + bf2f(u3.w));
    }
    for (; i + 4 <= i1; i += 4) {
      int s = colL[i + eo];
      ushort4 u = *(const ushort4*)&h1[(size_t)s * 64 + qfo];
      acc.x += bf2f(u.x); acc.y += bf2f(u.y);
      acc.z += bf2f(u.z); acc.w += bf2f(u.w);
    }
    if (eo < i1 - i) {
      int s = colL[i + eo];
      ushort4 u = *(const ushort4*)&h1[(size_t)s * 64 + qfo];
      acc.x += bf2f(u.x); acc.y += bf2f(u.y);
      acc.z += bf2f(u.z); acc.w += bf2f(u.w);
    }
#pragma unroll
    for (int m = 16; m <= 32; m <<= 1) {            // reduce over eo
      acc.x += __shfl_xor(acc.x, m, 64);
      acc.y += __shfl_xor(acc.y, m, 64);
      acc.z += __shfl_xor(acc.z, m, 64);
      acc.w += __shfl_xor(acc.w, m, 64);
    }
    float p = fmaxf(acc.x, 0.f) * sw[qfo] + fmaxf(acc.y, 0.f) * sw[qfo + 1] +
              fmaxf(acc.z, 0.f) * sw[qfo + 2] + fmaxf(acc.w, 0.f) * sw[qfo + 3];
#pragma unroll
    for (int m = 1; m <= 8; m <<= 1) p += __shfl_xor(p, m, 64);
    int node = b * 64 + r;
    if (lane == 0 && node < N_NODES) z[node] = p;
  }
}

// ---------------------------------------------------------------------------
// dispatch 3: per-graph sum over EDGES whose dst lies in the graph's node
// range of z[src] (layer-2 aggregation collapsed); /count; sigmoid.
__global__ __launch_bounds__(256) void graph_pool(const float* __restrict__ z,
                                                  const unsigned int* __restrict__ ebuf,
                                                  const int* __restrict__ gcur,
                                                  const int* __restrict__ batch,
                                                  float* __restrict__ out) {
  __shared__ float sacc[4];
  int g = blockIdx.x;
  int tid = threadIdx.x, lane = tid & 63, w = tid >> 6;

  int lo = 0, hi = N_NODES;
  while (lo < hi) { int mid = (lo + hi) >> 1; if (batch[mid] < g) lo = mid + 1; else hi = mid; }
  const int start = lo;
  hi = N_NODES;
  while (lo < hi) { int mid = (lo + hi) >> 1; if (batch[mid] < g + 1) lo = mid + 1; else hi = mid; }
  const int end = lo;

  float s = 0.f;
  if (end > start) {
    const int b0 = start >> 6, b1 = ((end - 1) >> 6) + 1;
    for (int b = b0; b < b1; b++) {
      int bc = gcur[b];
      if (bc > BKT_CAP) bc = BKT_CAP;
      const int q0 = b * BKT_CAP, q1 = q0 + bc;
      const int base = b << 6;
      for (int i = q0 + tid; i < q1; i += 256) {
        unsigned int u = ebuf[i];
        int d = base + (int)(u & 63);
        if (d >= start && d < end) s += z[u >> 6];
      }
    }
  }
#pragma unroll
  for (int off = 32; off; off >>= 1) s += __shfl_down(s, off, 64);
  if (lane == 0) sacc[w] = s;
  __syncthreads();
  if (tid == 0) {
    float v = sacc[0] + sacc[1] + sacc[2] + sacc[3];
    v /= fmaxf((float)(end - start), 1.f);
    out[g] = 1.f / (1.f + expf(-v));
  }
}

// ---------------------------------------------------------------------------
extern "C" void kernel_launch(void* const* d_in, const int* in_sizes, int n_in,
                              void* d_out, int out_size, void* d_ws, size_t ws_size,
                              hipStream_t stream) {
  const float* x     = (const float*)d_in[0];
  const int*   ei    = (const int*)d_in[1];   // [2, E]: src then dst
  const int*   batch = (const int*)d_in[2];
  const float* W1    = (const float*)d_in[3];
  const float* W2    = (const float*)d_in[4];
  const float* Wfc   = (const float*)d_in[5];
  float*       out   = (float*)d_out;

  const int* src = ei;
  const int* dst = ei + N_EDGES;

  // workspace layout (~13 MB, all disjoint, 16B-aligned sections)
  char* ws = (char*)d_ws;
  unsigned short* h1 = (unsigned short*)(ws);                  // [N,64] bf16
  float* z    = (float*)(ws + (size_t)N_NODES * DIM * 2);      // [N]
  float* w2fc = z + N_NODES;                                   // [64]
  unsigned short* w1sh = (unsigned short*)(w2fc + 64);         // [64][128]
  unsigned short* w1sl = w1sh + N_FEAT * DIM;                  // [64][128]
  int*   gcur = (int*)(w1sl + N_FEAT * DIM);                   // [NBKT] (pad 800)
  unsigned int* ebuf = (unsigned int*)(gcur + 800);            // [NBKT*BKT_CAP]

  // init: zero gcur (block 0) + split W1 into bf16 hi/lo [c][k] (blocks 1-32)
  init_split<<<33, 256, 0, stream>>>(W1, w1sh, w1sl, gcur);

  // slotted scatter (blocks 0..255) || w2fc || gemm1 (split-bf16 MFMA)
  fused_main<<<BH_BLK + 1 + GGRID, 256, 0, stream>>>(x, w1sh, w1sl, h1, src,
                                                     dst, gcur, ebuf, W2, Wfc,
                                                     w2fc);

  // per-bucket sort + layer-1 gather + relu + dot(W2@Wfc) -> z[N]
  gather_z_fused<<<NBKT, 1024, 0, stream>>>(h1, ebuf, gcur, w2fc, z);

  // per-graph edge-sum of z[src], mean, sigmoid
  graph_pool<<<N_GRAPHS, 256, 0, stream>>>(z, ebuf, gcur, batch, out);
}

// Round 8
// 138.548 us; speedup vs baseline: 1.0174x; 1.0174x over previous
//
#include <hip/hip_runtime.h>
#include <cmath>

#define N_NODES 50000
#define N_EDGES 800000
#define N_FEAT 128
#define DIM 64
#define N_GRAPHS 512
#define GGRID ((N_NODES + 63) / 64)         // 782 gemm1 tiles / buckets
#define NBKT GGRID                          // bucket = dst>>6
#define BH_BLK 256                          // scatter blocks (edge pass)
#define EPB (N_EDGES / BH_BLK)              // 3125 edges per scatter block
#define BKT_CAP 2048                        // fixed slot region per bucket

// bf16 storage helpers (RNE). Storage-only: all math in fp32.
__device__ __forceinline__ unsigned short f2bf(float f) {
  union { float f; unsigned int u; } v; v.f = f;
  return (unsigned short)((v.u + 0x7FFFu + ((v.u >> 16) & 1u)) >> 16);
}
__device__ __forceinline__ float bf2f(unsigned short u) {
  union { unsigned int u; float f; } v; v.u = (unsigned int)u << 16;
  return v.f;
}

// ---------------------------------------------------------------------------
// dispatch 0: tiny init — block 0 zeros gcur, block 1 computes w2fc = W2@Wfc.
// (Replaces hipMemsetAsync AND fused_main's w2fc branch arm: one fewer
// launch boundary, simpler fused_main indexing.)
__global__ __launch_bounds__(256) void init_k(int* __restrict__ gcur,
                                              const float* __restrict__ W2,
                                              const float* __restrict__ Wfc,
                                              float* __restrict__ w2fc) {
  const int tid = threadIdx.x;
  if (blockIdx.x == 0) {
    for (int i = tid; i < NBKT; i += 256) gcur[i] = 0;
  } else {
    if (tid < 64) {
      float s = 0.f;
#pragma unroll 8
      for (int j = 0; j < 64; j++) s += W2[tid * 64 + j] * Wfc[j];
      w2fc[tid] = s;
    }
  }
}

// ---------------------------------------------------------------------------
// GEMM body for gemm1: out[M][64] = A[M][128] @ W[128][64], bf16 output rows.
// (R0/R6 champion version — VALU fp32, 25.6KB LDS, 6 blocks/CU. Four gemm
// variants (VALU, MFMA+64KB, MFMA zero-LDS, MFMA+32KB) all measured within
// noise: the gemm arm is fully hidden under the scatter arm. Keep simplest.)
template<int K>
__device__ __forceinline__ void gemm_body_bf(const float* __restrict__ A,
                                             const float* __restrict__ W,
                                             unsigned short* __restrict__ out,
                                             int M, int row0, int tid,
                                             float* sX, float* sW) {
  const int tx = tid & 15, ty = tid >> 4;
  const int q = tid & 7, r0 = tid >> 3;
  float acc[4][4] = {};

  for (int kb = 0; kb < K; kb += 32) {
    __syncthreads();
    if ((kb & 63) == 0) {
#pragma unroll
      for (int i = 0; i < 16; i++)
        sW[i * 256 + tid] = W[kb * 64 + i * 256 + tid];
    }
#pragma unroll
    for (int rr = 0; rr < 64; rr += 32) {
      int r = r0 + rr;
      int gr = row0 + r;
      float4 v = make_float4(0.f, 0.f, 0.f, 0.f);
      if (gr < M) v = *(const float4*)&A[(size_t)gr * K + kb + q * 4];
      *(float4*)&sX[r * 36 + q * 4] = v;
    }
    __syncthreads();

    const int kw = kb & 63;
#pragma unroll 4
    for (int k = 0; k < 32; k += 4) {
      float4 wv[4];
#pragma unroll
      for (int kk = 0; kk < 4; kk++)
        wv[kk] = *(const float4*)&sW[(kw + k + kk) * 64 + tx * 4];
#pragma unroll
      for (int r = 0; r < 4; r++) {
        float4 xv = *(const float4*)&sX[(ty * 4 + r) * 36 + k];
        const float xs[4] = {xv.x, xv.y, xv.z, xv.w};
#pragma unroll
        for (int kk = 0; kk < 4; kk++) {
          acc[r][0] += xs[kk] * wv[kk].x;
          acc[r][1] += xs[kk] * wv[kk].y;
          acc[r][2] += xs[kk] * wv[kk].z;
          acc[r][3] += xs[kk] * wv[kk].w;
        }
      }
    }
  }

#pragma unroll
  for (int r = 0; r < 4; r++) {
    int gr = row0 + ty * 4 + r;
    if (gr < M) {
      ushort4 u;
      u.x = f2bf(acc[r][0]); u.y = f2bf(acc[r][1]);
      u.z = f2bf(acc[r][2]); u.w = f2bf(acc[r][3]);
      *(ushort4*)&out[(size_t)gr * 64 + tx * 4] = u;
    }
  }
}

// ---------------------------------------------------------------------------
// dispatch 1 (fused front-end):
//   blocks [0,BH_BLK):  slotted bucket scatter — dst staged into LDS during
//                       the histogram pass (pass 2 reads LDS, not global:
//                       removes the 3.2MB dst re-read + 800K load latencies),
//                       chunk reservation via atomicAdd on gcur[782], then
//                       LDS-cursor scatter of packed (src<<6)|dst_local.
//   blocks [BH_BLK..):  gemm1 (x@W1 -> h1 bf16). Scatter hides under gemm
//                       (R11 pairing; 25.6KB LDS -> 6 blocks/CU, all 1038
//                       blocks co-resident).
__global__ __launch_bounds__(256) void fused_main(
    const float* __restrict__ x, const float* __restrict__ W1,
    unsigned short* __restrict__ h1, const int* __restrict__ src,
    const int* __restrict__ dst, int* __restrict__ gcur,
    unsigned int* __restrict__ ebuf, const float* __restrict__ w2fc) {
  __shared__ float sX[64 * 36];
  __shared__ float sW[64 * 64];
  const int tid = threadIdx.x;
  if (blockIdx.x >= BH_BLK) {
    gemm_body_bf<N_FEAT>(x, W1, h1, N_NODES, (blockIdx.x - BH_BLK) * 64,
                         tid, sX, sW);
  } else {
    // LDS unions: sX = lh[782] | lbase[782] (6.3KB of 9.2KB)
    //             sW = lcur[782] | dstL[3125] (15.6KB of 16.4KB)
    int* lh = (int*)sX;
    int* lbase = lh + NBKT;
    int* lcur = (int*)sW;
    int* dstL = lcur + NBKT;
    for (int i = tid; i < NBKT; i += 256) { lh[i] = 0; lcur[i] = 0; }
    __syncthreads();
    const int base = blockIdx.x * EPB;
    for (int j = tid; j < EPB; j += 256) {          // pass 1: stage + hist
      int d = dst[base + j];
      dstL[j] = d;
      atomicAdd(&lh[d >> 6], 1);
    }
    __syncthreads();
    for (int i = tid; i < NBKT; i += 256) {         // chunk reservation
      int n = lh[i];
      lbase[i] = (n > 0) ? i * BKT_CAP + atomicAdd(&gcur[i], n) : 0;
    }
    __syncthreads();
    for (int j = tid; j < EPB; j += 256) {          // pass 2: LDS dst, scatter
      int d = dstL[j];
      int b = d >> 6;
      int pos = atomicAdd(&lcur[b], 1);
      unsigned int gpos = (unsigned int)(lbase[b] + pos);
      if (gpos < (unsigned int)((b + 1) * BKT_CAP))   // overflow guard
        ebuf[gpos] = ((unsigned int)src[base + j] << 6) | (unsigned int)(d & 63);
    }
  }
}

// ---------------------------------------------------------------------------
// dispatch 2: per-bucket LDS CSR sort + layer-1 gather + relu + dot(w2fc)
// -> z[node]. 782 blocks x 1024 threads (16 waves x 4 nodes). Bucket region
// is the fixed slot range [b*BKT_CAP, b*BKT_CAP + gcur[b]); edges staged
// into LDS during the count pass -> ebuf read ONCE.
__global__ __launch_bounds__(1024, 8) void gather_z_fused(
    const unsigned short* __restrict__ h1,
    const unsigned int* __restrict__ ebuf,
    const int* __restrict__ gcur,
    const float* __restrict__ w2fc,
    float* __restrict__ z) {
  __shared__ unsigned int eL[BKT_CAP];
  __shared__ int colL[BKT_CAP];
  __shared__ int lstart[64];
  __shared__ int lcur[64];
  __shared__ float sw[64];
  const int tid = threadIdx.x;
  const int b = blockIdx.x;
  const int p0 = b * BKT_CAP;
  int cnt = gcur[b];
  if (cnt > BKT_CAP) cnt = BKT_CAP;                 // never triggers

  if (tid < 64) { lstart[tid] = 0; sw[tid] = w2fc[tid]; }
  __syncthreads();
  for (int i = tid; i < cnt; i += 1024) {           // stage + count
    unsigned int u = ebuf[p0 + i];
    eL[i] = u;
    atomicAdd(&lstart[u & 63], 1);
  }
  __syncthreads();
  if (tid < 64) {
    int v = lstart[tid], s = v;
#pragma unroll
    for (int off = 1; off < 64; off <<= 1) {
      int t = __shfl_up(s, off, 64);
      if (tid >= off) s += t;
    }
    lstart[tid] = s - v;
    lcur[tid] = s - v;
  }
  __syncthreads();
  for (int i = tid; i < cnt; i += 1024) {           // scatter from LDS
    unsigned int u = eL[i];
    int pos = atomicAdd(&lcur[u & 63], 1);
    colL[pos] = (int)(u >> 6);
  }
  __syncthreads();

  const int lane = tid & 63, w = tid >> 6;
  const int eo = lane >> 4, qfo = (lane & 15) << 2;
#pragma unroll
  for (int ni = 0; ni < 4; ni++) {
    const int r = ni * 16 + w;
    const int i1 = lcur[r];
    int i = lstart[r];
    float4 acc = make_float4(0.f, 0.f, 0.f, 0.f);
    for (; i + 16 <= i1; i += 16) {
      int s0 = colL[i + eo];
      int s1 = colL[i + 4 + eo];
      int s2 = colL[i + 8 + eo];
      int s3 = colL[i + 12 + eo];
      ushort4 u0 = *(const ushort4*)&h1[(size_t)s0 * 64 + qfo];
      ushort4 u1 = *(const ushort4*)&h1[(size_t)s1 * 64 + qfo];
      ushort4 u2 = *(const ushort4*)&h1[(size_t)s2 * 64 + qfo];
      ushort4 u3 = *(const ushort4*)&h1[(size_t)s3 * 64 + qfo];
      acc.x += (bf2f(u0.x) + bf2f(u1.x)) + (bf2f(u2.x) + bf2f(u3.x));
      acc.y += (bf2f(u0.y) + bf2f(u1.y)) + (bf2f(u2.y) + bf2f(u3.y));
      acc.z += (bf2f(u0.z) + bf2f(u1.z)) + (bf2f(u2.z) + bf2f(u3.z));
      acc.w += (bf2f(u0.w) + bf2f(u1.w)) + (bf2f(u2.w) + bf2f(u3.w));
    }
    for (; i + 4 <= i1; i += 4) {
      int s = colL[i + eo];
      ushort4 u = *(const ushort4*)&h1[(size_t)s * 64 + qfo];
      acc.x += bf2f(u.x); acc.y += bf2f(u.y);
      acc.z += bf2f(u.z); acc.w += bf2f(u.w);
    }
    if (eo < i1 - i) {
      int s = colL[i + eo];
      ushort4 u = *(const ushort4*)&h1[(size_t)s * 64 + qfo];
      acc.x += bf2f(u.x); acc.y += bf2f(u.y);
      acc.z += bf2f(u.z); acc.w += bf2f(u.w);
    }
#pragma unroll
    for (int m = 16; m <= 32; m <<= 1) {            // reduce over eo
      acc.x += __shfl_xor(acc.x, m, 64);
      acc.y += __shfl_xor(acc.y, m, 64);
      acc.z += __shfl_xor(acc.z, m, 64);
      acc.w += __shfl_xor(acc.w, m, 64);
    }
    float p = fmaxf(acc.x, 0.f) * sw[qfo] + fmaxf(acc.y, 0.f) * sw[qfo + 1] +
              fmaxf(acc.z, 0.f) * sw[qfo + 2] + fmaxf(acc.w, 0.f) * sw[qfo + 3];
#pragma unroll
    for (int m = 1; m <= 8; m <<= 1) p += __shfl_xor(p, m, 64);
    int node = b * 64 + r;
    if (lane == 0 && node < N_NODES) z[node] = p;
  }
}

// ---------------------------------------------------------------------------
// dispatch 3: per-graph sum over EDGES whose dst lies in the graph's node
// range of z[src] (layer-2 aggregation collapsed); /count; sigmoid.
__global__ __launch_bounds__(256) void graph_pool(const float* __restrict__ z,
                                                  const unsigned int* __restrict__ ebuf,
                                                  const int* __restrict__ gcur,
                                                  const int* __restrict__ batch,
                                                  float* __restrict__ out) {
  __shared__ float sacc[4];
  int g = blockIdx.x;
  int tid = threadIdx.x, lane = tid & 63, w = tid >> 6;

  int lo = 0, hi = N_NODES;
  while (lo < hi) { int mid = (lo + hi) >> 1; if (batch[mid] < g) lo = mid + 1; else hi = mid; }
  const int start = lo;
  hi = N_NODES;
  while (lo < hi) { int mid = (lo + hi) >> 1; if (batch[mid] < g + 1) lo = mid + 1; else hi = mid; }
  const int end = lo;

  float s = 0.f;
  if (end > start) {
    const int b0 = start >> 6, b1 = ((end - 1) >> 6) + 1;
    for (int b = b0; b < b1; b++) {
      int bc = gcur[b];
      if (bc > BKT_CAP) bc = BKT_CAP;
      const int q0 = b * BKT_CAP, q1 = q0 + bc;
      const int base = b << 6;
      for (int i = q0 + tid; i < q1; i += 256) {
        unsigned int u = ebuf[i];
        int d = base + (int)(u & 63);
        if (d >= start && d < end) s += z[u >> 6];
      }
    }
  }
#pragma unroll
  for (int off = 32; off; off >>= 1) s += __shfl_down(s, off, 64);
  if (lane == 0) sacc[w] = s;
  __syncthreads();
  if (tid == 0) {
    float v = sacc[0] + sacc[1] + sacc[2] + sacc[3];
    v /= fmaxf((float)(end - start), 1.f);
    out[g] = 1.f / (1.f + expf(-v));
  }
}

// ---------------------------------------------------------------------------
extern "C" void kernel_launch(void* const* d_in, const int* in_sizes, int n_in,
                              void* d_out, int out_size, void* d_ws, size_t ws_size,
                              hipStream_t stream) {
  const float* x     = (const float*)d_in[0];
  const int*   ei    = (const int*)d_in[1];   // [2, E]: src then dst
  const int*   batch = (const int*)d_in[2];
  const float* W1    = (const float*)d_in[3];
  const float* W2    = (const float*)d_in[4];
  const float* Wfc   = (const float*)d_in[5];
  float*       out   = (float*)d_out;

  const int* src = ei;
  const int* dst = ei + N_EDGES;

  // workspace layout (~13 MB, all disjoint, 16B-aligned sections)
  char* ws = (char*)d_ws;
  unsigned short* h1 = (unsigned short*)(ws);                  // [N,64] bf16
  float* z    = (float*)(ws + (size_t)N_NODES * DIM * 2);      // [N]
  float* w2fc = z + N_NODES;                                   // [64]
  int*   gcur = (int*)(w2fc + 64);                             // [NBKT] (pad 800)
  unsigned int* ebuf = (unsigned int*)(gcur + 800);            // [NBKT*BKT_CAP]

  // init: zero gcur + w2fc = W2@Wfc (one tiny kernel, no memset dispatch)
  init_k<<<2, 256, 0, stream>>>(gcur, W2, Wfc, w2fc);

  // slotted scatter (blocks 0..255, dst LDS-staged) || gemm1 (x@W1 -> h1)
  fused_main<<<BH_BLK + GGRID, 256, 0, stream>>>(x, W1, h1, src, dst, gcur,
                                                 ebuf, w2fc);

  // per-bucket sort + layer-1 gather + relu + dot(W2@Wfc) -> z[N]
  gather_z_fused<<<NBKT, 1024, 0, stream>>>(h1, ebuf, gcur, w2fc, z);

  // per-graph edge-sum of z[src], mean, sigmoid
  graph_pool<<<N_GRAPHS, 256, 0, stream>>>(z, ebuf, gcur, batch, out);
}